// Round 6
// baseline (1013.402 us; speedup 1.0000x reference)
//
#include <hip/hip_runtime.h>

typedef unsigned short u16;
typedef short bf16x8 __attribute__((ext_vector_type(8)));
typedef u16 u16x8 __attribute__((ext_vector_type(8)));
typedef float f32x16 __attribute__((ext_vector_type(16)));

__device__ __forceinline__ float bf2f(u16 u) {
    union { unsigned u; float f; } c; c.u = ((unsigned)u) << 16; return c.f;
}
__device__ __forceinline__ u16 f2bf(float f) {
    union { float f; unsigned u; } c; c.f = f;
    unsigned r = c.u + 0x7FFFu + ((c.u >> 16) & 1u);
    return (u16)(r >> 16);
}
__device__ __forceinline__ float tanh_fast(float x) {
    float e = __expf(2.0f * x);
    return 1.0f - 2.0f / (e + 1.0f);
}
__device__ __forceinline__ void gll16(const void* g, void* l) {
    __builtin_amdgcn_global_load_lds((const __attribute__((address_space(1))) void*)g,
                                     (__attribute__((address_space(3))) void*)l, 16, 0, 0);
}

#define BAR() do { __builtin_amdgcn_sched_barrier(0); __builtin_amdgcn_s_barrier(); \
                   __builtin_amdgcn_sched_barrier(0); } while (0)

// ---------------- f32 -> bf16 convert, 8 elems/thread ----------------
__global__ __launch_bounds__(256) void cvt_f32_bf16(const float* __restrict__ src,
                                                    u16* __restrict__ dst, int n8) {
    int i = blockIdx.x * blockDim.x + threadIdx.x;
    int stride = gridDim.x * blockDim.x;
    for (; i < n8; i += stride) {
        const float4* s = (const float4*)(src + (size_t)i * 8);
        float4 a = s[0], b = s[1];
        u16x8 o;
        o[0] = f2bf(a.x); o[1] = f2bf(a.y); o[2] = f2bf(a.z); o[3] = f2bf(a.w);
        o[4] = f2bf(b.x); o[5] = f2bf(b.y); o[6] = f2bf(b.z); o[7] = f2bf(b.w);
        *(u16x8*)(dst + (size_t)i * 8) = o;
    }
}

// ---------------- mq = tanh(Wm @ m_q + bm), one wave per output ----------------
__global__ __launch_bounds__(256) void mq_kernel(const float* __restrict__ Wm,
                                                 const float* __restrict__ q,
                                                 const float* __restrict__ bm,
                                                 float* __restrict__ mq, int D) {
    int w = threadIdx.x >> 6, l = threadIdx.x & 63;
    int e = blockIdx.x * 4 + w;
    const float* wp = Wm + (size_t)e * D;
    float s = 0.f;
    for (int j = 0; j < D; j += 256) {
        float4 wv = *(const float4*)(wp + j + l * 4);
        float4 qv = *(const float4*)(q + j + l * 4);
        s += wv.x * qv.x + wv.y * qv.y + wv.z * qv.z + wv.w * qv.w;
    }
    #pragma unroll
    for (int o = 32; o >= 1; o >>= 1) s += __shfl_xor(s, o);
    if (l == 0) mq[e] = tanh_fast(s + bm[e]);
}

// ---------------- C[M,N] = A[M,K] @ B[N,K]^T : 256x256, 32x32x16 MFMA ----------------
// 8 waves (2M x 4N), BK=64, 3-bit XOR LDS swizzle, 4 phases/K-tile, 1 barrier/phase,
// reads pipelined 1 phase ahead (r5 ledger: W3=vmcnt(6) seals A0/B0(t+1) for ph4
// read-ahead; W4=vmcnt(4) seals A1/B1(t+1) for ph1/ph2 of t+1).
// Per wave per quadrant: 2 m-frags x 1 n-frag x 4 k-steps = 8 MFMA (32x32x16).
// EPI=0: C = bf16( tanh(acc+bias[col]) * gate[col] );  EPI=1: C = bf16(acc+bias[col])
template <int EPI>
__global__ __launch_bounds__(512, 2) void gemm8(const u16* __restrict__ A,
                                                const u16* __restrict__ B,
                                                const float* __restrict__ bias,
                                                const float* __restrict__ gate,
                                                u16* __restrict__ C,
                                                int M, int N, int K) {
    __shared__ u16 sh[65536];            // 128 KiB: A slots 0..3 @0, B slots 0..3 @65536
    char* LDS = (char*)sh;
    const int K2 = K * 2;
    const int KT = K >> 6;               // K-tiles of 64 (must be even)

    const int tid = threadIdx.x;
    const int w = tid >> 6, l = tid & 63;
    const int wm = w >> 2, wn = w & 3;

    // XCD-aware swizzle (nwg = 1024, divisible by 8)
    int orig = blockIdx.x + gridDim.x * blockIdx.y;
    int nwg = gridDim.x * gridDim.y;
    int id = ((nwg & 7) == 0) ? ((orig & 7) * (nwg >> 3) + (orig >> 3)) : orig;
    const int tileN = (id % gridDim.x) * 256;
    const int tileM = (id / gridDim.x) * 256;

    // ---- staging geometry (pre-swizzled global source, linear LDS dest) ----
    // physical LDS byte = wj*1024 + l*16 -> row = wj*8 + (l>>3), phys slot = l&7.
    // logical slot = phys ^ (row&7) = (l&7) ^ (l>>3)  ->  global col byte:
    const int r0 = (w * 2) * 8 + (l >> 3);
    const int r1 = (w * 2 + 1) * 8 + (l >> 3);
    const int cc = ((l & 7) ^ (l >> 3)) << 4;
    const char* srcA0 = (const char*)A + (size_t)(tileM + r0) * K2 + cc;
    const char* srcA1 = (const char*)A + (size_t)(tileM + r1) * K2 + cc;
    const char* srcB0 = (const char*)B + (size_t)(tileN + r0) * K2 + cc;
    const char* srcB1 = (const char*)B + (size_t)(tileN + r1) * K2 + cc;
    const int ldc0 = (w * 2) * 1024, ldc1 = (w * 2 + 1) * 1024;

#define STG_A(tk, h) do { size_t go = (size_t)(tk) * 128 + (size_t)(h) * 128 * K2; \
    int sb = ((((tk) & 1) * 2 + (h)) * 16384); \
    gll16(srcA0 + go, LDS + sb + ldc0); gll16(srcA1 + go, LDS + sb + ldc1); } while (0)
#define STG_B(tk, h) do { size_t go = (size_t)(tk) * 128 + (size_t)(h) * 128 * K2; \
    int sb = 65536 + ((((tk) & 1) * 2 + (h)) * 16384); \
    gll16(srcB0 + go, LDS + sb + ldc0); gll16(srcB1 + go, LDS + sb + ldc1); } while (0)

    // ---- reader bases (32x32x16 fragments) ----
    // A-frag: row = wm*64 + mf*32 + (l&31); k-step s: logical slot = 2s + (l>>5),
    // physical = logical ^ (row&7).  B-frag: row = wn*32 + (l&31), same slots.
    const int l5 = l >> 5;
    const int sw = l & 7;
    const int rowA32 = (wm * 64 + (l & 31)) * 128;
    const int rowB32 = (wn * 32 + (l & 31)) * 128;
    const char* pA_0 = LDS + rowA32 + ((((0) + l5) ^ sw) << 4);
    const char* pA_1 = LDS + rowA32 + ((((2) + l5) ^ sw) << 4);
    const char* pA_2 = LDS + rowA32 + ((((4) + l5) ^ sw) << 4);
    const char* pA_3 = LDS + rowA32 + ((((6) + l5) ^ sw) << 4);
    const char* pB_0 = LDS + 65536 + rowB32 + ((((0) + l5) ^ sw) << 4);
    const char* pB_1 = LDS + 65536 + rowB32 + ((((2) + l5) ^ sw) << 4);
    const char* pB_2 = LDS + 65536 + rowB32 + ((((4) + l5) ^ sw) << 4);
    const char* pB_3 = LDS + 65536 + rowB32 + ((((6) + l5) ^ sw) << 4);

    f32x16 acc[2][2][2] = {};                 // [qm][mf][qn]
    bf16x8 afA[2][4], afB[2][4], bb0[4], bb1[4];

#define RD_A(DST, SLOT)                                                         \
    _Pragma("unroll")                                                           \
    for (int mf = 0; mf < 2; ++mf) {                                            \
        DST[mf][0] = *(const bf16x8*)(pA_0 + (SLOT) + mf * 4096);               \
        DST[mf][1] = *(const bf16x8*)(pA_1 + (SLOT) + mf * 4096);               \
        DST[mf][2] = *(const bf16x8*)(pA_2 + (SLOT) + mf * 4096);               \
        DST[mf][3] = *(const bf16x8*)(pA_3 + (SLOT) + mf * 4096);               \
    }
#define RD_B(DST, SLOT)                                                         \
    DST[0] = *(const bf16x8*)(pB_0 + (SLOT));                                   \
    DST[1] = *(const bf16x8*)(pB_1 + (SLOT));                                   \
    DST[2] = *(const bf16x8*)(pB_2 + (SLOT));                                   \
    DST[3] = *(const bf16x8*)(pB_3 + (SLOT));

    // ---- prologue: tile0 (all 4 halves) + tile1 A0,B0; seal tile0; pre-read ----
    STG_A(0, 0); STG_B(0, 0); STG_A(0, 1); STG_B(0, 1);
    STG_A(1, 0); STG_B(1, 0);
    asm volatile("s_waitcnt vmcnt(4)" ::: "memory");
    BAR();
    RD_A(afA, 0)
    RD_B(bb0, 0)

#define MFMA_CLUSTER(QM, QN, AF, BB)                                            \
    __builtin_amdgcn_s_setprio(1);                                              \
    _Pragma("unroll")                                                           \
    for (int s = 0; s < 4; ++s)                                                 \
        _Pragma("unroll")                                                       \
        for (int mf = 0; mf < 2; ++mf)                                          \
            acc[QM][mf][QN] = __builtin_amdgcn_mfma_f32_32x32x16_bf16(          \
                AF[mf][s], BB[s], acc[QM][mf][QN], 0, 0, 0);                    \
    __builtin_amdgcn_s_setprio(0);

#define ITER(t, P) do {                                                         \
    constexpr int S1 = (2 * (P) + 1) * 16384;                                   \
    constexpr int SN = (2 * (1 - (P))) * 16384;                                 \
    /* ph1: MFMA Q00(afA,bb0) || read bb1 <- B1(t) || stage A1(t+1) */          \
    if ((t) + 1 < KT) STG_A((t) + 1, 1);                                        \
    RD_B(bb1, S1)                                                               \
    MFMA_CLUSTER(0, 0, afA, bb0)                                                \
    BAR();                                                                      \
    /* ph2: MFMA Q01(afA,bb1) || read afB <- A1(t) || stage B1(t+1) */          \
    if ((t) + 1 < KT) STG_B((t) + 1, 1);                                        \
    RD_A(afB, S1)                                                               \
    MFMA_CLUSTER(0, 1, afA, bb1)                                                \
    BAR();                                                                      \
    /* ph3: MFMA Q10(afB,bb0) || stage A0(t+2); W3 seals A0/B0(t+1) */          \
    if ((t) + 2 < KT) { STG_A((t) + 2, 0);                                      \
        asm volatile("s_waitcnt vmcnt(6)" ::: "memory"); }                      \
    else if ((t) + 1 < KT)                                                      \
        asm volatile("s_waitcnt vmcnt(4)" ::: "memory");                        \
    MFMA_CLUSTER(1, 0, afB, bb0)                                                \
    BAR();                                                                      \
    /* ph4: MFMA Q11(afB,bb1) || stage B0(t+2); W4 seals A1/B1(t+1);            \
       read-ahead afA,bb0 <- A0,B0(t+1) */                                      \
    if ((t) + 2 < KT) { STG_B((t) + 2, 0);                                      \
        asm volatile("s_waitcnt vmcnt(4)" ::: "memory"); }                      \
    else if ((t) + 1 < KT)                                                      \
        asm volatile("s_waitcnt vmcnt(0)" ::: "memory");                        \
    if ((t) + 1 < KT) {                                                         \
        RD_A(afA, SN)                                                           \
        RD_B(bb0, SN)                                                           \
    }                                                                           \
    MFMA_CLUSTER(1, 1, afB, bb1)                                                \
    BAR();                                                                      \
} while (0)

    for (int tt = 0; tt < KT; tt += 2) {
        ITER(tt, 0);
        ITER(tt + 1, 1);
    }
#undef ITER
#undef MFMA_CLUSTER
#undef RD_A
#undef RD_B
#undef STG_A
#undef STG_B

    // ---- epilogue: 32x32 C/D layout col = lane&31, row = (reg&3)+8*(reg>>2)+4*(lane>>5) ----
    const int cl32 = l & 31;
    const int rb = 4 * l5;
    #pragma unroll
    for (int qn = 0; qn < 2; ++qn) {
        const int col = tileN + qn * 128 + wn * 32 + cl32;
        const float bs = bias[col];
        float gt = 0.f;
        if (EPI == 0) gt = gate[col];
        #pragma unroll
        for (int qm = 0; qm < 2; ++qm)
            #pragma unroll
            for (int mf = 0; mf < 2; ++mf) {
                const int row0 = tileM + qm * 128 + wm * 64 + mf * 32 + rb;
                #pragma unroll
                for (int r = 0; r < 16; ++r) {
                    const int row = row0 + (r & 3) + 8 * (r >> 2);
                    float v = acc[qm][mf][qn][r] + bs;
                    if (EPI == 0) v = tanh_fast(v) * gt;
                    C[(size_t)row * N + col] = f2bf(v);
                }
            }
    }
}

// ---------------- row softmax + weighted sum + m_q_new ----------------
__global__ __launch_bounds__(256) void softmax_out(const u16* __restrict__ logits,
                                                   const float* __restrict__ hidden,
                                                   const float* __restrict__ m_q,
                                                   float* __restrict__ out,
                                                   int D, int R) {
    const int r = blockIdx.x;
    const int t = threadIdx.x;
    const int w = t >> 6, l = t & 63;
    const u16* lp = logits + (size_t)r * D + t * 8;
    const float* hp = hidden + (size_t)r * D + t * 8;

    bf16x8 lv = *(const bf16x8*)lp;
    float lf[8];
    #pragma unroll
    for (int j = 0; j < 8; ++j) lf[j] = bf2f((u16)lv[j]);
    float4 h0 = *(const float4*)hp;
    float4 h1 = *(const float4*)(hp + 4);
    float hv[8] = {h0.x, h0.y, h0.z, h0.w, h1.x, h1.y, h1.z, h1.w};

    float m = lf[0];
    #pragma unroll
    for (int j = 1; j < 8; ++j) m = fmaxf(m, lf[j]);
    #pragma unroll
    for (int o = 32; o >= 1; o >>= 1) m = fmaxf(m, __shfl_xor(m, o));

    __shared__ float red[8];
    if (l == 0) red[w] = m;
    __syncthreads();
    m = fmaxf(fmaxf(red[0], red[1]), fmaxf(red[2], red[3]));
    __syncthreads();

    float se = 0.f, sh = 0.f;
    #pragma unroll
    for (int j = 0; j < 8; ++j) {
        float e = __expf(lf[j] - m);
        se += e;
        sh += e * hv[j];
    }
    #pragma unroll
    for (int o = 32; o >= 1; o >>= 1) { se += __shfl_xor(se, o); sh += __shfl_xor(sh, o); }
    if (l == 0) { red[w] = se; red[4 + w] = sh; }
    __syncthreads();
    if (t == 0) {
        float SE = red[0] + red[1] + red[2] + red[3];
        float SH = red[4] + red[5] + red[6] + red[7];
        float o = SH / SE;
        out[r] = o;
        out[R + r] = m_q[r & (D - 1)] + o;
    }
}

extern "C" void kernel_launch(void* const* d_in, const int* in_sizes, int n_in,
                              void* d_out, int out_size, void* d_ws, size_t ws_size,
                              hipStream_t stream) {
    const float* hidden = (const float*)d_in[0];
    const float* m_q    = (const float*)d_in[1];
    const float* Wq     = (const float*)d_in[2];
    const float* bq     = (const float*)d_in[3];
    const float* Wm     = (const float*)d_in[4];
    const float* bm     = (const float*)d_in[5];
    const float* Wa     = (const float*)d_in[6];
    const float* ba     = (const float*)d_in[7];
    float* out = (float*)d_out;

    const int D = 2048;
    const int M = 16 * 2048;  // B*S = 32768

    char* ws = (char*)d_ws;
    size_t oH  = 0;
    size_t oS  = oH  + (size_t)M * D * 2;   // Sg bf16
    size_t oWq = oS  + (size_t)M * D * 2;
    size_t oWa = oWq + (size_t)D * D * 2;
    size_t oMq = oWa + (size_t)D * D * 2;
    size_t need = oMq + (size_t)D * sizeof(float);
    if (ws_size < need) return;

    u16* hbf    = (u16*)(ws + oH);
    u16* Sg     = (u16*)(ws + oS);
    u16* Wqb    = (u16*)(ws + oWq);
    u16* Wab    = (u16*)(ws + oWa);
    float* mq   = (float*)(ws + oMq);
    u16* logits = hbf;  // alias: hidden_bf16 dead after GEMM1

    cvt_f32_bf16<<<4096, 256, 0, stream>>>(hidden, hbf, M * D / 8);
    cvt_f32_bf16<<<1024, 256, 0, stream>>>(Wq, Wqb, D * D / 8);
    cvt_f32_bf16<<<1024, 256, 0, stream>>>(Wa, Wab, D * D / 8);
    mq_kernel<<<D / 4, 256, 0, stream>>>(Wm, m_q, bm, mq, D);

    dim3 grid(D / 256, M / 256);  // (8, 128)
    gemm8<0><<<grid, 512, 0, stream>>>(hbf, Wqb, bq, mq, Sg, M, D, D);
    gemm8<1><<<grid, 512, 0, stream>>>(Sg, Wab, ba, nullptr, logits, M, D, D);

    softmax_out<<<M, 256, 0, stream>>>(logits, hidden, m_q, out, D, M);
}

// Round 7
// 663.935 us; speedup vs baseline: 1.5264x; 1.5264x over previous
//
#include <hip/hip_runtime.h>

typedef unsigned short u16;
typedef short bf16x8 __attribute__((ext_vector_type(8)));
typedef u16 u16x8 __attribute__((ext_vector_type(8)));
typedef float f32x4 __attribute__((ext_vector_type(4)));

__device__ __forceinline__ float bf2f(u16 u) {
    union { unsigned u; float f; } c; c.u = ((unsigned)u) << 16; return c.f;
}
__device__ __forceinline__ u16 f2bf(float f) {
    union { float f; unsigned u; } c; c.f = f;
    unsigned r = c.u + 0x7FFFu + ((c.u >> 16) & 1u);
    return (u16)(r >> 16);
}
__device__ __forceinline__ float tanh_fast(float x) {
    float e = __expf(2.0f * x);
    return 1.0f - 2.0f / (e + 1.0f);
}
__device__ __forceinline__ void gll16(const void* g, void* l) {
    __builtin_amdgcn_global_load_lds((const __attribute__((address_space(1))) void*)g,
                                     (__attribute__((address_space(3))) void*)l, 16, 0, 0);
}

#define BAR() do { __builtin_amdgcn_sched_barrier(0); __builtin_amdgcn_s_barrier(); \
                   __builtin_amdgcn_sched_barrier(0); } while (0)

// ---------------- f32 -> bf16 convert, 8 elems/thread ----------------
__global__ __launch_bounds__(256) void cvt_f32_bf16(const float* __restrict__ src,
                                                    u16* __restrict__ dst, int n8) {
    int i = blockIdx.x * blockDim.x + threadIdx.x;
    int stride = gridDim.x * blockDim.x;
    for (; i < n8; i += stride) {
        const float4* s = (const float4*)(src + (size_t)i * 8);
        float4 a = s[0], b = s[1];
        u16x8 o;
        o[0] = f2bf(a.x); o[1] = f2bf(a.y); o[2] = f2bf(a.z); o[3] = f2bf(a.w);
        o[4] = f2bf(b.x); o[5] = f2bf(b.y); o[6] = f2bf(b.z); o[7] = f2bf(b.w);
        *(u16x8*)(dst + (size_t)i * 8) = o;
    }
}

// ---------------- mq = tanh(Wm @ m_q + bm), one wave per output ----------------
__global__ __launch_bounds__(256) void mq_kernel(const float* __restrict__ Wm,
                                                 const float* __restrict__ q,
                                                 const float* __restrict__ bm,
                                                 float* __restrict__ mq, int D) {
    int w = threadIdx.x >> 6, l = threadIdx.x & 63;
    int e = blockIdx.x * 4 + w;
    const float* wp = Wm + (size_t)e * D;
    float s = 0.f;
    for (int j = 0; j < D; j += 256) {
        float4 wv = *(const float4*)(wp + j + l * 4);
        float4 qv = *(const float4*)(q + j + l * 4);
        s += wv.x * qv.x + wv.y * qv.y + wv.z * qv.z + wv.w * qv.w;
    }
    #pragma unroll
    for (int o = 32; o >= 1; o >>= 1) s += __shfl_xor(s, o);
    if (l == 0) mq[e] = tanh_fast(s + bm[e]);
}

// ---------------- C[M,N] = A[M,K] @ B[N,K]^T : 256x256 8-phase, deep-prefetch ledger ----
// 8 waves (2M x 4N), BK=64, 16x16x32 MFMA, 3-bit XOR LDS swizzle (0 conflicts),
// reads in consuming phase pre-barrier (m201 style). vmcnt ledger with >=3-phase
// wait age: ph1 vmcnt(6) retires A1/B1(t) [ages 4/3 ph], seals B1(t)->ph2, A1(t)->ph3;
// ph4 vmcnt(8) retires A0/B0(t+1) [age 5 ph], seals them for ph1(t+1). 8 loads
// always in flight; tail: ph4 vmcnt(4) when t+2>=KT, ph1 vmcnt(0) when t+1>=KT.
// EPI=0: C = bf16( tanh(acc+bias[col]) * gate[col] );  EPI=1: C = bf16(acc+bias[col])
template <int EPI>
__global__ __launch_bounds__(512, 2) void gemm8(const u16* __restrict__ A,
                                                const u16* __restrict__ B,
                                                const float* __restrict__ bias,
                                                const float* __restrict__ gate,
                                                u16* __restrict__ C,
                                                int M, int N, int K) {
    __shared__ u16 sh[65536];            // 128 KiB: A slots 0..3 @0, B slots 0..3 @65536
    char* LDS = (char*)sh;
    const int K2 = K * 2;
    const int KT = K >> 6;               // K-tiles of 64 (must be even)

    const int tid = threadIdx.x;
    const int w = tid >> 6, l = tid & 63;
    const int wm = w >> 2, wn = w & 3;

    // XCD-aware swizzle (nwg = 1024, divisible by 8)
    int orig = blockIdx.x + gridDim.x * blockIdx.y;
    int nwg = gridDim.x * gridDim.y;
    int id = ((nwg & 7) == 0) ? ((orig & 7) * (nwg >> 3) + (orig >> 3)) : orig;
    const int tileN = (id % gridDim.x) * 256;
    const int tileM = (id / gridDim.x) * 256;

    // ---- staging geometry (pre-swizzled global source, linear LDS dest) ----
    // physical LDS byte = wj*1024 + l*16 -> row = wj*8 + (l>>3), phys slot = l&7.
    // logical slot = phys ^ (row&7) = (l&7) ^ (l>>3)  ->  global col byte:
    const int r0 = (w * 2) * 8 + (l >> 3);
    const int r1 = (w * 2 + 1) * 8 + (l >> 3);
    const int cc = ((l & 7) ^ (l >> 3)) << 4;
    const char* srcA0 = (const char*)A + (size_t)(tileM + r0) * K2 + cc;
    const char* srcA1 = (const char*)A + (size_t)(tileM + r1) * K2 + cc;
    const char* srcB0 = (const char*)B + (size_t)(tileN + r0) * K2 + cc;
    const char* srcB1 = (const char*)B + (size_t)(tileN + r1) * K2 + cc;
    const int ldc0 = (w * 2) * 1024, ldc1 = (w * 2 + 1) * 1024;

#define STG_A(tk, h) do { size_t go = (size_t)(tk) * 128 + (size_t)(h) * 128 * K2; \
    int sb = ((((tk) & 1) * 2 + (h)) * 16384); \
    gll16(srcA0 + go, LDS + sb + ldc0); gll16(srcA1 + go, LDS + sb + ldc1); } while (0)
#define STG_B(tk, h) do { size_t go = (size_t)(tk) * 128 + (size_t)(h) * 128 * K2; \
    int sb = 65536 + ((((tk) & 1) * 2 + (h)) * 16384); \
    gll16(srcB0 + go, LDS + sb + ldc0); gll16(srcB1 + go, LDS + sb + ldc1); } while (0)

    // ---- reader bases: base VGPR + literal offset ----
    const int sw = l & 7;
    const int rowA = (wm * 64 + (l & 15)) * 128;
    const int rowB = (wn * 32 + (l & 15)) * 128;
    const int ck0 = (((l >> 4) ^ sw) << 4);
    const int ck1 = (((4 + (l >> 4)) ^ sw) << 4);
    const char* pA0 = LDS + rowA + ck0;
    const char* pA1 = LDS + rowA + ck1;
    const char* pB0 = LDS + 65536 + rowB + ck0;
    const char* pB1 = LDS + 65536 + rowB + ck1;

    f32x4 acc[2][4][2][2] = {};
    bf16x8 afA[4][2], afB[4][2], bb0[2][2], bb1[2][2];

#define RD_A(DST, SLOT)                                                         \
    _Pragma("unroll")                                                           \
    for (int fm = 0; fm < 4; ++fm) {                                            \
        DST[fm][0] = *(const bf16x8*)(pA0 + (SLOT) + fm * 2048);                \
        DST[fm][1] = *(const bf16x8*)(pA1 + (SLOT) + fm * 2048);                \
    }
#define RD_B(DST, SLOT)                                                         \
    _Pragma("unroll")                                                           \
    for (int fn = 0; fn < 2; ++fn) {                                            \
        DST[fn][0] = *(const bf16x8*)(pB0 + (SLOT) + fn * 2048);                \
        DST[fn][1] = *(const bf16x8*)(pB1 + (SLOT) + fn * 2048);                \
    }

    // ---- prologue: tile0 all 4 halves + tile1 A0,B0; seal tile0 ----
    STG_A(0, 0); STG_B(0, 0); STG_A(0, 1); STG_B(0, 1);
    STG_A(1, 0); STG_B(1, 0);
    asm volatile("s_waitcnt vmcnt(4)" ::: "memory");
    BAR();

#define MFMA_CLUSTER(QM, QN, AF, BF)                                            \
    __builtin_amdgcn_s_setprio(1);                                              \
    _Pragma("unroll")                                                           \
    for (int fm = 0; fm < 4; ++fm)                                              \
        _Pragma("unroll")                                                       \
        for (int fn = 0; fn < 2; ++fn) {                                        \
            acc[QM][fm][QN][fn] = __builtin_amdgcn_mfma_f32_16x16x32_bf16(      \
                AF[fm][0], BF[fn][0], acc[QM][fm][QN][fn], 0, 0, 0);            \
            acc[QM][fm][QN][fn] = __builtin_amdgcn_mfma_f32_16x16x32_bf16(      \
                AF[fm][1], BF[fn][1], acc[QM][fm][QN][fn], 0, 0, 0);            \
        }                                                                       \
    __builtin_amdgcn_s_setprio(0);

#define ITER(t, P) do {                                                         \
    constexpr int S0 = (2 * (P)) * 16384;                                       \
    constexpr int S1 = (2 * (P) + 1) * 16384;                                   \
    /* ph1: read A0(t)+B0(t); stage A1(t+1); vmcnt(6) seals B1(t),A1(t) */      \
    RD_A(afA, S0)                                                               \
    RD_B(bb0, S0)                                                               \
    if ((t) + 1 < KT) { STG_A((t) + 1, 1);                                      \
        asm volatile("s_waitcnt vmcnt(6)" ::: "memory"); }                      \
    else                                                                        \
        asm volatile("s_waitcnt vmcnt(0)" ::: "memory");                        \
    BAR();                                                                      \
    MFMA_CLUSTER(0, 0, afA, bb0)                                                \
    BAR();                                                                      \
    /* ph2: read B1(t); stage B1(t+1) */                                        \
    RD_B(bb1, S1)                                                               \
    if ((t) + 1 < KT) STG_B((t) + 1, 1);                                        \
    BAR();                                                                      \
    MFMA_CLUSTER(0, 1, afA, bb1)                                                \
    BAR();                                                                      \
    /* ph3: read A1(t); stage A0(t+2) */                                        \
    RD_A(afB, S1)                                                               \
    if ((t) + 2 < KT) STG_A((t) + 2, 0);                                        \
    BAR();                                                                      \
    MFMA_CLUSTER(1, 0, afB, bb0)                                                \
    BAR();                                                                      \
    /* ph4: stage B0(t+2); vmcnt(8) retires+seals A0/B0(t+1) for ph1(t+1) */    \
    if ((t) + 2 < KT) { STG_B((t) + 2, 0);                                      \
        asm volatile("s_waitcnt vmcnt(8)" ::: "memory"); }                      \
    else if ((t) + 1 < KT)                                                      \
        asm volatile("s_waitcnt vmcnt(4)" ::: "memory");                        \
    BAR();                                                                      \
    MFMA_CLUSTER(1, 1, afB, bb1)                                                \
    BAR();                                                                      \
} while (0)

    for (int tt = 0; tt < KT; tt += 2) {
        ITER(tt, 0);
        ITER(tt + 1, 1);
    }
#undef ITER
#undef MFMA_CLUSTER
#undef RD_A
#undef RD_B
#undef STG_A
#undef STG_B

    // ---- epilogue: C/D layout col = lane&15, row = (lane>>4)*4 + reg ----
    const int cr = (l >> 4) * 4;
    const int cl = l & 15;
    #pragma unroll
    for (int qn = 0; qn < 2; ++qn)
        #pragma unroll
        for (int fn = 0; fn < 2; ++fn) {
            const int col = tileN + qn * 128 + wn * 32 + fn * 16 + cl;
            const float bs = bias[col];
            float gt = 0.f;
            if (EPI == 0) gt = gate[col];
            #pragma unroll
            for (int qm = 0; qm < 2; ++qm)
                #pragma unroll
                for (int fm = 0; fm < 4; ++fm)
                    #pragma unroll
                    for (int r = 0; r < 4; ++r) {
                        const int row = tileM + qm * 128 + wm * 64 + fm * 16 + cr + r;
                        float v = acc[qm][fm][qn][fn][r] + bs;
                        if (EPI == 0) v = tanh_fast(v) * gt;
                        C[(size_t)row * N + col] = f2bf(v);
                    }
        }
}

// ---------------- row softmax + weighted sum + m_q_new ----------------
__global__ __launch_bounds__(256) void softmax_out(const u16* __restrict__ logits,
                                                   const float* __restrict__ hidden,
                                                   const float* __restrict__ m_q,
                                                   float* __restrict__ out,
                                                   int D, int R) {
    const int r = blockIdx.x;
    const int t = threadIdx.x;
    const int w = t >> 6, l = t & 63;
    const u16* lp = logits + (size_t)r * D + t * 8;
    const float* hp = hidden + (size_t)r * D + t * 8;

    bf16x8 lv = *(const bf16x8*)lp;
    float lf[8];
    #pragma unroll
    for (int j = 0; j < 8; ++j) lf[j] = bf2f((u16)lv[j]);
    float4 h0 = *(const float4*)hp;
    float4 h1 = *(const float4*)(hp + 4);
    float hv[8] = {h0.x, h0.y, h0.z, h0.w, h1.x, h1.y, h1.z, h1.w};

    float m = lf[0];
    #pragma unroll
    for (int j = 1; j < 8; ++j) m = fmaxf(m, lf[j]);
    #pragma unroll
    for (int o = 32; o >= 1; o >>= 1) m = fmaxf(m, __shfl_xor(m, o));

    __shared__ float red[8];
    if (l == 0) red[w] = m;
    __syncthreads();
    m = fmaxf(fmaxf(red[0], red[1]), fmaxf(red[2], red[3]));
    __syncthreads();

    float se = 0.f, sh = 0.f;
    #pragma unroll
    for (int j = 0; j < 8; ++j) {
        float e = __expf(lf[j] - m);
        se += e;
        sh += e * hv[j];
    }
    #pragma unroll
    for (int o = 32; o >= 1; o >>= 1) { se += __shfl_xor(se, o); sh += __shfl_xor(sh, o); }
    if (l == 0) { red[w] = se; red[4 + w] = sh; }
    __syncthreads();
    if (t == 0) {
        float SE = red[0] + red[1] + red[2] + red[3];
        float SH = red[4] + red[5] + red[6] + red[7];
        float o = SH / SE;
        out[r] = o;
        out[R + r] = m_q[r & (D - 1)] + o;
    }
}

extern "C" void kernel_launch(void* const* d_in, const int* in_sizes, int n_in,
                              void* d_out, int out_size, void* d_ws, size_t ws_size,
                              hipStream_t stream) {
    const float* hidden = (const float*)d_in[0];
    const float* m_q    = (const float*)d_in[1];
    const float* Wq     = (const float*)d_in[2];
    const float* bq     = (const float*)d_in[3];
    const float* Wm     = (const float*)d_in[4];
    const float* bm     = (const float*)d_in[5];
    const float* Wa     = (const float*)d_in[6];
    const float* ba     = (const float*)d_in[7];
    float* out = (float*)d_out;

    const int D = 2048;
    const int M = 16 * 2048;  // B*S = 32768

    char* ws = (char*)d_ws;
    size_t oH  = 0;
    size_t oS  = oH  + (size_t)M * D * 2;   // Sg bf16
    size_t oWq = oS  + (size_t)M * D * 2;
    size_t oWa = oWq + (size_t)D * D * 2;
    size_t oMq = oWa + (size_t)D * D * 2;
    size_t need = oMq + (size_t)D * sizeof(float);
    if (ws_size < need) return;

    u16* hbf    = (u16*)(ws + oH);
    u16* Sg     = (u16*)(ws + oS);
    u16* Wqb    = (u16*)(ws + oWq);
    u16* Wab    = (u16*)(ws + oWa);
    float* mq   = (float*)(ws + oMq);
    u16* logits = hbf;  // alias: hidden_bf16 dead after GEMM1

    cvt_f32_bf16<<<4096, 256, 0, stream>>>(hidden, hbf, M * D / 8);
    cvt_f32_bf16<<<1024, 256, 0, stream>>>(Wq, Wqb, D * D / 8);
    cvt_f32_bf16<<<1024, 256, 0, stream>>>(Wa, Wab, D * D / 8);
    mq_kernel<<<D / 4, 256, 0, stream>>>(Wm, m_q, bm, mq, D);

    dim3 grid(D / 256, M / 256);  // (8, 128)
    gemm8<0><<<grid, 512, 0, stream>>>(hbf, Wqb, bq, mq, Sg, M, D, D);
    gemm8<1><<<grid, 512, 0, stream>>>(Sg, Wab, ba, nullptr, logits, M, D, D);

    softmax_out<<<M, 256, 0, stream>>>(logits, hidden, m_q, out, D, M);
}